// Round 1
// baseline (226.630 us; speedup 1.0000x reference)
//
#include <hip/hip_runtime.h>

// One thread per gaussian. Block = 256 threads.
// Per block: 256 quats (float4, coalesced), 768 scale floats staged via LDS
// (192 coalesced float4 loads), 2304 output floats staged in LDS and drained
// as 576 coalesced float4 stores.

__global__ __launch_bounds__(256) void cov_main_kernel(
    const float4* __restrict__ rot4,
    const float4* __restrict__ scale4,
    float4* __restrict__ out4)
{
    __shared__ float s_scale[768];                 // 256 * 3
    __shared__ __align__(16) float s_out[2304];    // 256 * 9
    const int t = threadIdx.x;
    const long long b = blockIdx.x;

    // Stage this block's scales: 768 floats = 192 float4, coalesced.
    if (t < 192) {
        ((float4*)s_scale)[t] = scale4[b * 192 + t];
    }
    // Quaternion load: 16B/lane, perfectly coalesced.
    float4 q = rot4[b * 256 + t];
    __syncthreads();

    // stride-3 LDS read: gcd(3,32)=1 -> 2 lanes/bank over wave64, free.
    const float s0 = s_scale[t * 3 + 0];
    const float s1 = s_scale[t * 3 + 1];
    const float s2 = s_scale[t * 3 + 2];

    const float invn = rsqrtf(q.x * q.x + q.y * q.y + q.z * q.z + q.w * q.w);
    const float w = q.x * invn, x = q.y * invn, y = q.z * invn, z = q.w * invn;

    const float r00 = 1.f - 2.f * (y * y + z * z);
    const float r01 = 2.f * (x * y - w * z);
    const float r02 = 2.f * (x * z + w * y);
    const float r10 = 2.f * (x * y + w * z);
    const float r11 = 1.f - 2.f * (x * x + z * z);
    const float r12 = 2.f * (y * z - w * x);
    const float r20 = 2.f * (x * z - w * y);
    const float r21 = 2.f * (y * z + w * x);
    const float r22 = 1.f - 2.f * (x * x + y * y);

    // M[i][j] = R[i][j] * s[j]
    const float m00 = r00 * s0, m01 = r01 * s1, m02 = r02 * s2;
    const float m10 = r10 * s0, m11 = r11 * s1, m12 = r12 * s2;
    const float m20 = r20 * s0, m21 = r21 * s1, m22 = r22 * s2;

    // cov = M * M^T (symmetric)
    const float c00 = m00 * m00 + m01 * m01 + m02 * m02;
    const float c01 = m00 * m10 + m01 * m11 + m02 * m12;
    const float c02 = m00 * m20 + m01 * m21 + m02 * m22;
    const float c11 = m10 * m10 + m11 * m11 + m12 * m12;
    const float c12 = m10 * m20 + m11 * m21 + m12 * m22;
    const float c22 = m20 * m20 + m21 * m21 + m22 * m22;

    // stride-9 LDS write: gcd(9,32)=1 -> 2-way aliasing over wave64, free.
    float* so = &s_out[t * 9];
    so[0] = c00; so[1] = c01; so[2] = c02;
    so[3] = c01; so[4] = c11; so[5] = c12;
    so[6] = c02; so[7] = c12; so[8] = c22;
    __syncthreads();

    // Drain 576 float4 per block, fully coalesced 16B stores.
    const float4* sv = (const float4*)s_out;
    float4* ob = out4 + b * 576;
    ob[t]       = sv[t];
    ob[t + 256] = sv[t + 256];
    if (t < 64) ob[t + 512] = sv[t + 512];
}

// Tail path (not expected to launch for N=4,000,000): scalar, bounds-checked.
__global__ void cov_tail_kernel(
    const float* __restrict__ rot,
    const float* __restrict__ scale,
    float* __restrict__ out,
    int start, int n)
{
    int i = start + blockIdx.x * blockDim.x + threadIdx.x;
    if (i >= n) return;
    const float qw = rot[i * 4 + 0], qx = rot[i * 4 + 1];
    const float qy = rot[i * 4 + 2], qz = rot[i * 4 + 3];
    const float s0 = scale[i * 3 + 0], s1 = scale[i * 3 + 1], s2 = scale[i * 3 + 2];
    const float invn = rsqrtf(qw * qw + qx * qx + qy * qy + qz * qz);
    const float w = qw * invn, x = qx * invn, y = qy * invn, z = qz * invn;
    const float r00 = 1.f - 2.f * (y * y + z * z);
    const float r01 = 2.f * (x * y - w * z);
    const float r02 = 2.f * (x * z + w * y);
    const float r10 = 2.f * (x * y + w * z);
    const float r11 = 1.f - 2.f * (x * x + z * z);
    const float r12 = 2.f * (y * z - w * x);
    const float r20 = 2.f * (x * z - w * y);
    const float r21 = 2.f * (y * z + w * x);
    const float r22 = 1.f - 2.f * (x * x + y * y);
    const float m00 = r00 * s0, m01 = r01 * s1, m02 = r02 * s2;
    const float m10 = r10 * s0, m11 = r11 * s1, m12 = r12 * s2;
    const float m20 = r20 * s0, m21 = r21 * s1, m22 = r22 * s2;
    float* o = out + (size_t)i * 9;
    o[0] = m00 * m00 + m01 * m01 + m02 * m02;
    o[1] = m00 * m10 + m01 * m11 + m02 * m12;
    o[2] = m00 * m20 + m01 * m21 + m02 * m22;
    o[3] = o[1];
    o[4] = m10 * m10 + m11 * m11 + m12 * m12;
    o[5] = m10 * m20 + m11 * m21 + m12 * m22;
    o[6] = o[2];
    o[7] = o[5];
    o[8] = m20 * m20 + m21 * m21 + m22 * m22;
}

extern "C" void kernel_launch(void* const* d_in, const int* in_sizes, int n_in,
                              void* d_out, int out_size, void* d_ws, size_t ws_size,
                              hipStream_t stream) {
    const float* rot   = (const float*)d_in[0];   // (N,4) fp32
    const float* scale = (const float*)d_in[1];   // (N,3) fp32
    float* out = (float*)d_out;                   // (N,3,3) fp32

    const int N = in_sizes[0] / 4;
    const int nfull = N / 256;          // full blocks of 256 gaussians
    const int rem_start = nfull * 256;
    const int rem = N - rem_start;

    if (nfull > 0) {
        cov_main_kernel<<<nfull, 256, 0, stream>>>(
            (const float4*)rot, (const float4*)scale, (float4*)out);
    }
    if (rem > 0) {
        cov_tail_kernel<<<(rem + 255) / 256, 256, 0, stream>>>(
            rot, scale, out, rem_start, N);
    }
}